// Round 16
// baseline (149.828 us; speedup 1.0000x reference)
//
#include <hip/hip_runtime.h>

// GCN 2-layer forward. N=50000, E=800000, D: 256 -> 128 -> 64.
// Round 16: revert to round-11 structure (best, 136.6us); single change:
// GEMM1 now overlaps with BUCKET (4:1 interleave) instead of count.
// Count (returning-atomic, ~33us floor) runs standalone. 9 launches.

static constexpr int SCAN_CHUNK = 1024;
static constexpr int CPAD = 16;  // counter stride (ints)

using short8 = __attribute__((ext_vector_type(8))) short;
using f32x4  = __attribute__((ext_vector_type(4))) float;

__device__ inline unsigned short bf16rne(float f) {
  unsigned u = __float_as_uint(f);
  u += 0x7fffu + ((u >> 16) & 1u);
  return (unsigned short)(u >> 16);
}
__device__ inline float bflo(unsigned u) { return __uint_as_float(u << 16); }
__device__ inline float bfhi(unsigned u) { return __uint_as_float(u & 0xffff0000u); }

// Fragment-pack: Wtp[i], i = ((kc*NT+nt)*64 + l)*8 + e,
// k = kc*32 + (l>>4)*8 + e, n = nt*16 + (l&15).
__device__ inline void wtp_pack(const float* __restrict__ W,
                                unsigned short* __restrict__ Wtp,
                                int i, int K, int C) {
  int e = i & 7;
  int l = (i >> 3) & 63;
  int rest = i >> 9;
  int NT = C / 16;
  int nt = rest % NT;
  int kc = rest / NT;
  int k = kc * 32 + (l >> 4) * 8 + e;
  int n = nt * 16 + (l & 15);
  Wtp[i] = bf16rne(W[(size_t)k * C + n]);
}

__global__ __launch_bounds__(256) void k_prep(int* __restrict__ cnt, int nz,
                                              const float* __restrict__ W1,
                                              unsigned short* __restrict__ wtp1,
                                              const float* __restrict__ W2,
                                              unsigned short* __restrict__ wtp2) {
  int i = blockIdx.x * 256 + threadIdx.x;
  if (i < nz) cnt[i] = 0;
  if (i < 256 * 128) wtp_pack(W1, wtp1, i, 256, 128);
  if (i < 128 * 64) wtp_pack(W2, wtp2, i, 128, 64);
}

// standalone count: 4 edges/thread, 1 returning atomic each (padded counters)
__global__ __launch_bounds__(256) void k_count(const int* __restrict__ dst,
                                               int* __restrict__ cnt,
                                               int* __restrict__ epos, int E) {
  const int base = blockIdx.x * 1024 + threadIdx.x;
  int d[4];
#pragma unroll
  for (int j = 0; j < 4; ++j) {
    int e = base + j * 256;
    d[j] = (e < E) ? dst[e] : -1;
  }
#pragma unroll
  for (int j = 0; j < 4; ++j) {
    int e = base + j * 256;
    if (e < E) epos[e] = atomicAdd(&cnt[(size_t)d[j] * CPAD], 1);
  }
}

// ---- 2-kernel scan (chunk-base add folded into consumers) ----
__global__ __launch_bounds__(256) void k_scan1(const int* __restrict__ in,
                                               int* __restrict__ out,
                                               int* __restrict__ sums, int n) {
  __shared__ int sd[256];
  const int base = blockIdx.x * SCAN_CHUNK;
  const int tid = threadIdx.x;
  int v[4], tot = 0;
#pragma unroll
  for (int j = 0; j < 4; ++j) {
    int idx = base + tid * 4 + j;
    v[j] = (idx < n) ? in[(size_t)idx * CPAD] : 0;
    tot += v[j];
  }
  sd[tid] = tot;
  __syncthreads();
  for (int d = 1; d < 256; d <<= 1) {
    int t = (tid >= d) ? sd[tid - d] : 0;
    __syncthreads();
    sd[tid] += t;
    __syncthreads();
  }
  if (tid == 255) sums[blockIdx.x] = sd[255];
  int run = sd[tid] - tot;
#pragma unroll
  for (int j = 0; j < 4; ++j) {
    int idx = base + tid * 4 + j;
    if (idx < n) out[idx] = run;
    run += v[j];
  }
}

__global__ __launch_bounds__(64) void k_scan2(int* __restrict__ sums, int n) {
  int tid = threadIdx.x;
  int o = (tid < n) ? sums[tid] : 0;
  int v = o;
  for (int d = 1; d < 64; d <<= 1) {
    int t = __shfl_up(v, d, 64);
    if (tid >= d) v += t;
  }
  if (tid < n) sums[tid] = v - o;  // exclusive
}

// ---- heterogeneous: bid%5==4 -> GEMM1 (f32 in, bf16 out, unscaled),
//      else -> bucket (atomic-free scattered csr write). 4:1 interleave.
__global__ __launch_bounds__(256, 4) void k_bucket_gemm1(
    const int* __restrict__ src, const int* __restrict__ dst,
    const float* __restrict__ w, const int* __restrict__ row_ptr,
    const int* __restrict__ chunks, const int* __restrict__ epos,
    int2* __restrict__ csr, int E,
    const float* __restrict__ A, const unsigned short* __restrict__ Wtp,
    unsigned short* __restrict__ H, int n) {
  const int bid = blockIdx.x;
  const int r5 = bid % 5;
  if (r5 != 4) {
    // ---- bucket: csr[rp(dst)+chunks+epos] = (src, raw w) ----
    const int wid = (bid / 5) * 4 + r5;
    int e = wid * 256 + threadIdx.x;
    if (e < E) {
      int d = dst[e];
      int pos = row_ptr[d] + chunks[d >> 10] + epos[e];
      csr[pos] = make_int2(src[e], __float_as_int(w[e]));
    }
    return;
  }
  // ---- GEMM1: K=256, C=128 ----
  constexpr int K = 256, C = 128, NT = C / 16, KCH = K / 32;
  const int gwid = bid / 5;
  const int w4 = threadIdx.x >> 6;
  const int l = threadIdx.x & 63;
  const int lm = l & 15;
  const int lk = (l >> 4) * 8;
  const int row0 = (gwid * 4 + w4) * 16;
  if (row0 >= n) return;
  const int m = row0 + lm;
  const bool valid = m < n;
  const size_t arow = (size_t)(valid ? m : 0) * K;

  short8 af[KCH];
  {
    float4 a[2 * KCH];
#pragma unroll
    for (int c = 0; c < KCH; ++c) {
      if (valid) {
        a[2 * c]     = *(const float4*)(A + arow + c * 32 + lk);
        a[2 * c + 1] = *(const float4*)(A + arow + c * 32 + lk + 4);
      } else {
        a[2 * c] = a[2 * c + 1] = make_float4(0.f, 0.f, 0.f, 0.f);
      }
    }
#pragma unroll
    for (int c = 0; c < KCH; ++c) {
      af[c][0] = (short)bf16rne(a[2 * c].x);     af[c][1] = (short)bf16rne(a[2 * c].y);
      af[c][2] = (short)bf16rne(a[2 * c].z);     af[c][3] = (short)bf16rne(a[2 * c].w);
      af[c][4] = (short)bf16rne(a[2 * c + 1].x); af[c][5] = (short)bf16rne(a[2 * c + 1].y);
      af[c][6] = (short)bf16rne(a[2 * c + 1].z); af[c][7] = (short)bf16rne(a[2 * c + 1].w);
    }
  }
  f32x4 acc[NT] = {};
  const short8* B = (const short8*)Wtp;
#pragma unroll
  for (int c = 0; c < KCH; ++c)
#pragma unroll
    for (int nt = 0; nt < NT; ++nt)
      acc[nt] = __builtin_amdgcn_mfma_f32_16x16x32_bf16(af[c], B[(c * NT + nt) * 64 + l],
                                                        acc[nt], 0, 0, 0);
  const int orow = row0 + (l >> 4) * 4;
#pragma unroll
  for (int nt = 0; nt < NT; ++nt)
#pragma unroll
    for (int r = 0; r < 4; ++r) {
      int g = orow + r;
      if (g < n) H[(size_t)g * C + nt * 16 + lm] = bf16rne(acc[nt][r]);
    }
}

// dinv[i] = rsqrt(1 + sum of raw w over row i)
__global__ __launch_bounds__(256) void k_deg_dinv(const int* __restrict__ row_ptr,
                                                  const int* __restrict__ chunks,
                                                  const int2* __restrict__ csr,
                                                  float* __restrict__ dinv, int n) {
  int i = blockIdx.x * 256 + threadIdx.x;
  if (i >= n) return;
  const int e0 = row_ptr[i] + chunks[i >> 10];
  const int e1 = row_ptr[i + 1] + chunks[(i + 1) >> 10];
  float s = 1.0f;
  int e = e0;
  for (; e + 4 <= e1; e += 4) {
    float w0 = __int_as_float(csr[e].y), w1 = __int_as_float(csr[e + 1].y);
    float w2 = __int_as_float(csr[e + 2].y), w3 = __int_as_float(csr[e + 3].y);
    s += (w0 + w1) + (w2 + w3);
  }
  for (; e < e1; ++e) s += __int_as_float(csr[e].y);
  dinv[i] = rsqrtf(s);
}

// H = A @ W (bf16 in/out, unscaled) — layer 2
template <int K, int C>
__global__ __launch_bounds__(256, 4) void k_gemm_bf(
    const unsigned short* __restrict__ A, const unsigned short* __restrict__ Wtp,
    unsigned short* __restrict__ H, int n) {
  constexpr int NT = C / 16, KCH = K / 32;
  const int w = threadIdx.x >> 6;
  const int l = threadIdx.x & 63;
  const int lm = l & 15;
  const int lk = (l >> 4) * 8;
  const int row0 = (blockIdx.x * 4 + w) * 16;
  if (row0 >= n) return;
  const int m = row0 + lm;
  const bool valid = m < n;
  const size_t arow = (size_t)(valid ? m : 0) * K;
  short8 af[KCH];
#pragma unroll
  for (int c = 0; c < KCH; ++c)
    af[c] = valid ? *(const short8*)(A + arow + c * 32 + lk)
                  : short8{0, 0, 0, 0, 0, 0, 0, 0};
  f32x4 acc[NT] = {};
  const short8* B = (const short8*)Wtp;
#pragma unroll
  for (int c = 0; c < KCH; ++c)
#pragma unroll
    for (int nt = 0; nt < NT; ++nt)
      acc[nt] = __builtin_amdgcn_mfma_f32_16x16x32_bf16(af[c], B[(c * NT + nt) * 64 + l],
                                                        acc[nt], 0, 0, 0);
  const int orow = row0 + (l >> 4) * 4;
#pragma unroll
  for (int nt = 0; nt < NT; ++nt)
#pragma unroll
    for (int r = 0; r < 4; ++r) {
      int g = orow + r;
      if (g < n) H[(size_t)g * C + nt * 16 + lm] = bf16rne(acc[nt][r]);
    }
}

// out[i] = relu( dinv_i*( dinv_i*h[i] + sum_e dinv[src_e]*w_e*h[src_e] ) + b )
template <int C, bool OUTF32>
__global__ __launch_bounds__(256) void k_aggregate(
    const int* __restrict__ row_ptr, const int* __restrict__ chunks,
    const int2* __restrict__ csr, const unsigned short* __restrict__ h,
    const float* __restrict__ dinv, const float* __restrict__ bias,
    void* __restrict__ outp, int n) {
  constexpr int LPN = C / 8;      // lanes per node, 16B granules
  constexpr int NPB = 256 / LPN;  // nodes per block
  const int g = threadIdx.x % LPN;
  const int i = blockIdx.x * NPB + threadIdx.x / LPN;
  if (i >= n) return;
  const float di = dinv[i];
  const uint4* h4 = (const uint4*)h;
  uint4 hv = h4[(size_t)i * LPN + g];
  float a0 = di * bflo(hv.x), a1 = di * bfhi(hv.x);
  float a2 = di * bflo(hv.y), a3 = di * bfhi(hv.y);
  float a4 = di * bflo(hv.z), a5 = di * bfhi(hv.z);
  float a6 = di * bflo(hv.w), a7 = di * bfhi(hv.w);
  const int e1 = row_ptr[i + 1] + chunks[(i + 1) >> 10];
  int e = row_ptr[i] + chunks[i >> 10];
  for (; e + 8 <= e1; e += 8) {
    int2 c[8];
    uint4 v[8];
    float ds[8];
#pragma unroll
    for (int j = 0; j < 8; ++j) c[j] = csr[e + j];
#pragma unroll
    for (int j = 0; j < 8; ++j) v[j] = h4[(size_t)c[j].x * LPN + g];
#pragma unroll
    for (int j = 0; j < 8; ++j) ds[j] = dinv[c[j].x];
#pragma unroll
    for (int j = 0; j < 8; ++j) {
      float wj = __int_as_float(c[j].y) * ds[j];
      a0 = fmaf(bflo(v[j].x), wj, a0); a1 = fmaf(bfhi(v[j].x), wj, a1);
      a2 = fmaf(bflo(v[j].y), wj, a2); a3 = fmaf(bfhi(v[j].y), wj, a3);
      a4 = fmaf(bflo(v[j].z), wj, a4); a5 = fmaf(bfhi(v[j].z), wj, a5);
      a6 = fmaf(bflo(v[j].w), wj, a6); a7 = fmaf(bfhi(v[j].w), wj, a7);
    }
  }
  for (; e + 4 <= e1; e += 4) {
    int2 c[4];
    uint4 v[4];
    float ds[4];
#pragma unroll
    for (int j = 0; j < 4; ++j) c[j] = csr[e + j];
#pragma unroll
    for (int j = 0; j < 4; ++j) v[j] = h4[(size_t)c[j].x * LPN + g];
#pragma unroll
    for (int j = 0; j < 4; ++j) ds[j] = dinv[c[j].x];
#pragma unroll
    for (int j = 0; j < 4; ++j) {
      float wj = __int_as_float(c[j].y) * ds[j];
      a0 = fmaf(bflo(v[j].x), wj, a0); a1 = fmaf(bfhi(v[j].x), wj, a1);
      a2 = fmaf(bflo(v[j].y), wj, a2); a3 = fmaf(bfhi(v[j].y), wj, a3);
      a4 = fmaf(bflo(v[j].z), wj, a4); a5 = fmaf(bfhi(v[j].z), wj, a5);
      a6 = fmaf(bflo(v[j].w), wj, a6); a7 = fmaf(bfhi(v[j].w), wj, a7);
    }
  }
  for (; e < e1; ++e) {
    int2 c = csr[e];
    float wj = __int_as_float(c.y) * dinv[c.x];
    uint4 v = h4[(size_t)c.x * LPN + g];
    a0 = fmaf(bflo(v.x), wj, a0); a1 = fmaf(bfhi(v.x), wj, a1);
    a2 = fmaf(bflo(v.y), wj, a2); a3 = fmaf(bfhi(v.y), wj, a3);
    a4 = fmaf(bflo(v.z), wj, a4); a5 = fmaf(bfhi(v.z), wj, a5);
    a6 = fmaf(bflo(v.w), wj, a6); a7 = fmaf(bfhi(v.w), wj, a7);
  }
  const float4* b4 = (const float4*)bias;
  float4 bb0 = b4[g * 2], bb1 = b4[g * 2 + 1];
  a0 = fmaxf(fmaf(a0, di, bb0.x), 0.f); a1 = fmaxf(fmaf(a1, di, bb0.y), 0.f);
  a2 = fmaxf(fmaf(a2, di, bb0.z), 0.f); a3 = fmaxf(fmaf(a3, di, bb0.w), 0.f);
  a4 = fmaxf(fmaf(a4, di, bb1.x), 0.f); a5 = fmaxf(fmaf(a5, di, bb1.y), 0.f);
  a6 = fmaxf(fmaf(a6, di, bb1.z), 0.f); a7 = fmaxf(fmaf(a7, di, bb1.w), 0.f);
  if (OUTF32) {
    float4* o4 = (float4*)outp;
    o4[(size_t)i * (C / 4) + g * 2]     = make_float4(a0, a1, a2, a3);
    o4[(size_t)i * (C / 4) + g * 2 + 1] = make_float4(a4, a5, a6, a7);
  } else {
    uint4 o;
    o.x = (unsigned)bf16rne(a0) | ((unsigned)bf16rne(a1) << 16);
    o.y = (unsigned)bf16rne(a2) | ((unsigned)bf16rne(a3) << 16);
    o.z = (unsigned)bf16rne(a4) | ((unsigned)bf16rne(a5) << 16);
    o.w = (unsigned)bf16rne(a6) | ((unsigned)bf16rne(a7) << 16);
    ((uint4*)outp)[(size_t)i * LPN + g] = o;
  }
}

extern "C" void kernel_launch(void* const* d_in, const int* in_sizes, int n_in,
                              void* d_out, int out_size, void* d_ws, size_t ws_size,
                              hipStream_t stream) {
  (void)n_in; (void)out_size; (void)ws_size;
  const float* x  = (const float*)d_in[0];
  const int*   ei = (const int*)d_in[1];
  const float* ew = (const float*)d_in[2];
  const float* W1 = (const float*)d_in[3];
  const float* b1 = (const float*)d_in[4];
  const float* W2 = (const float*)d_in[5];
  const float* b2 = (const float*)d_in[6];
  float* out = (float*)d_out;

  const int N = in_sizes[0] / 256;  // 50000
  const int E = in_sizes[2];        // 800000
  const int* src = ei;
  const int* dst = ei + E;

  // workspace layout (4-byte units)
  float* ws      = (float*)d_ws;
  float* dinv    = ws;                                   // N          (50176)
  int*   row_ptr = (int*)(ws + 50176);                   // N+1        (50176)
  int*   chunks  = row_ptr + 50176;                      // 64         (256)
  int*   cnt     = chunks + 256;                         // (N+1)*16   (800256)
  int*   epos    = cnt + 800256;                         // E          (800256)
  int2*  csr     = (int2*)(epos + 800256);               // E int2     (1600512)
  unsigned short* h1   = (unsigned short*)((int*)csr + 2 * 800256);  // N*128 bf16
  unsigned short* o1   = h1 + (size_t)50000 * 128;       // N*128 bf16
  unsigned short* wtp1 = o1 + (size_t)50000 * 128;       // 128*256 bf16
  unsigned short* wtp2 = wtp1 + 128 * 256;               // 64*128 bf16
  unsigned short* h2   = h1;                             // alias (h1 dead after agg1)

  const int nz = (N + 1) * CPAD;
  const int nchunks = (N + 1 + SCAN_CHUNK - 1) / SCAN_CHUNK;  // 49
  const int GB = (N + 63) / 64;                               // 782 gemm1 blocks
  // bucket needs ceil(E/256)=3125 blocks; 4:1 interleave with GB=782 gemm
  // blocks gives 782*5=3910 total, bucket share 3128 >= 3125.

  k_prep<<<(nz + 255) / 256, 256, 0, stream>>>(cnt, nz, W1, wtp1, W2, wtp2);
  k_count<<<(E + 1023) / 1024, 256, 0, stream>>>(dst, cnt, epos, E);
  k_scan1<<<nchunks, 256, 0, stream>>>(cnt, row_ptr, chunks, N + 1);
  k_scan2<<<1, 64, 0, stream>>>(chunks, nchunks);
  k_bucket_gemm1<<<GB * 5, 256, 0, stream>>>(src, dst, ew, row_ptr, chunks, epos,
                                             csr, E, x, wtp1, h1, N);
  k_deg_dinv<<<(N + 255) / 256, 256, 0, stream>>>(row_ptr, chunks, csr, dinv, N);

  k_aggregate<128, false><<<(N + 15) / 16, 256, 0, stream>>>(row_ptr, chunks, csr,
                                                             h1, dinv, b1, o1, N);
  k_gemm_bf<128, 64><<<(N + 63) / 64, 256, 0, stream>>>(o1, wtp2, h2, N);
  k_aggregate<64, true><<<(N + 31) / 32, 256, 0, stream>>>(row_ptr, chunks, csr,
                                                           h2, dinv, b2, out, N);
}

// Round 17
// 136.843 us; speedup vs baseline: 1.0949x; 1.0949x over previous
//
#include <hip/hip_runtime.h>

// GCN 2-layer forward. N=50000, E=800000, D: 256 -> 128 -> 64.
// Round 17: PURE REVERT to round-11 (best measured: 136.6us).
// Structure: parity-interleaved heterogeneous P1 (even blocks = atomic count,
// odd blocks = GEMM1), dinv gathered per-edge in aggregation, 9 launches.
// Remaining costs are structural floors (see journal): 800k returning atomics
// ~33us, aggregation gathers at ~6.8 TB/s effective, 9 launch gaps.

static constexpr int SCAN_CHUNK = 1024;
static constexpr int CPAD = 16;  // counter stride (ints) = one 64B line

using short8 = __attribute__((ext_vector_type(8))) short;
using f32x4  = __attribute__((ext_vector_type(4))) float;

__device__ inline unsigned short bf16rne(float f) {
  unsigned u = __float_as_uint(f);
  u += 0x7fffu + ((u >> 16) & 1u);
  return (unsigned short)(u >> 16);
}
__device__ inline float bflo(unsigned u) { return __uint_as_float(u << 16); }
__device__ inline float bfhi(unsigned u) { return __uint_as_float(u & 0xffff0000u); }

// Fragment-pack: Wtp[i], i = ((kc*NT+nt)*64 + l)*8 + e,
// k = kc*32 + (l>>4)*8 + e, n = nt*16 + (l&15).
__device__ inline void wtp_pack(const float* __restrict__ W,
                                unsigned short* __restrict__ Wtp,
                                int i, int K, int C) {
  int e = i & 7;
  int l = (i >> 3) & 63;
  int rest = i >> 9;
  int NT = C / 16;
  int nt = rest % NT;
  int kc = rest / NT;
  int k = kc * 32 + (l >> 4) * 8 + e;
  int n = nt * 16 + (l & 15);
  Wtp[i] = bf16rne(W[(size_t)k * C + n]);
}

__global__ __launch_bounds__(256) void k_prep(int* __restrict__ cnt, int nz,
                                              const float* __restrict__ W1,
                                              unsigned short* __restrict__ wtp1,
                                              const float* __restrict__ W2,
                                              unsigned short* __restrict__ wtp2) {
  int i = blockIdx.x * 256 + threadIdx.x;
  if (i < nz) cnt[i] = 0;
  if (i < 256 * 128) wtp_pack(W1, wtp1, i, 256, 128);
  if (i < 128 * 64) wtp_pack(W2, wtp2, i, 128, 64);
}

// ---- heterogeneous P1, parity-interleaved: even blocks count, odd blocks
// GEMM1 (unscaled, f32 input). CB == GB here (both 782).
__global__ __launch_bounds__(256, 4) void k_count_gemm1(
    const int* __restrict__ dst, int* __restrict__ cnt, int* __restrict__ epos,
    int E, int CB,
    const float* __restrict__ A, const unsigned short* __restrict__ Wtp,
    unsigned short* __restrict__ H, int n) {
  const int bid = blockIdx.x;
  const int wid = bid >> 1;
  if ((bid & 1) == 0) {
    // ---- count: 4 edges/thread, 1 returning atomic each ----
    const int base = wid * 1024 + threadIdx.x;
    int d[4];
#pragma unroll
    for (int j = 0; j < 4; ++j) {
      int e = base + j * 256;
      d[j] = (e < E) ? dst[e] : -1;
    }
#pragma unroll
    for (int j = 0; j < 4; ++j) {
      int e = base + j * 256;
      if (e < E) epos[e] = atomicAdd(&cnt[(size_t)d[j] * CPAD], 1);
    }
    return;
  }
  // ---- GEMM1: K=256, C=128, f32 A, bf16 out, no scaling ----
  constexpr int K = 256, C = 128, NT = C / 16, KCH = K / 32;
  const int w = threadIdx.x >> 6;
  const int l = threadIdx.x & 63;
  const int lm = l & 15;
  const int lk = (l >> 4) * 8;
  const int row0 = (wid * 4 + w) * 16;
  if (row0 >= n) return;
  const int m = row0 + lm;
  const bool valid = m < n;
  const size_t arow = (size_t)(valid ? m : 0) * K;

  short8 af[KCH];
  {
    float4 a[2 * KCH];
#pragma unroll
    for (int c = 0; c < KCH; ++c) {
      if (valid) {
        a[2 * c]     = *(const float4*)(A + arow + c * 32 + lk);
        a[2 * c + 1] = *(const float4*)(A + arow + c * 32 + lk + 4);
      } else {
        a[2 * c] = a[2 * c + 1] = make_float4(0.f, 0.f, 0.f, 0.f);
      }
    }
#pragma unroll
    for (int c = 0; c < KCH; ++c) {
      af[c][0] = (short)bf16rne(a[2 * c].x);     af[c][1] = (short)bf16rne(a[2 * c].y);
      af[c][2] = (short)bf16rne(a[2 * c].z);     af[c][3] = (short)bf16rne(a[2 * c].w);
      af[c][4] = (short)bf16rne(a[2 * c + 1].x); af[c][5] = (short)bf16rne(a[2 * c + 1].y);
      af[c][6] = (short)bf16rne(a[2 * c + 1].z); af[c][7] = (short)bf16rne(a[2 * c + 1].w);
    }
  }
  f32x4 acc[NT] = {};
  const short8* B = (const short8*)Wtp;
#pragma unroll
  for (int c = 0; c < KCH; ++c)
#pragma unroll
    for (int nt = 0; nt < NT; ++nt)
      acc[nt] = __builtin_amdgcn_mfma_f32_16x16x32_bf16(af[c], B[(c * NT + nt) * 64 + l],
                                                        acc[nt], 0, 0, 0);
  const int orow = row0 + (l >> 4) * 4;
#pragma unroll
  for (int nt = 0; nt < NT; ++nt)
#pragma unroll
    for (int r = 0; r < 4; ++r) {
      int g = orow + r;
      if (g < n) H[(size_t)g * C + nt * 16 + lm] = bf16rne(acc[nt][r]);
    }
}

// ---- 2-kernel scan (chunk-base add folded into consumers) ----
__global__ __launch_bounds__(256) void k_scan1(const int* __restrict__ in,
                                               int* __restrict__ out,
                                               int* __restrict__ sums, int n) {
  __shared__ int sd[256];
  const int base = blockIdx.x * SCAN_CHUNK;
  const int tid = threadIdx.x;
  int v[4], tot = 0;
#pragma unroll
  for (int j = 0; j < 4; ++j) {
    int idx = base + tid * 4 + j;
    v[j] = (idx < n) ? in[(size_t)idx * CPAD] : 0;
    tot += v[j];
  }
  sd[tid] = tot;
  __syncthreads();
  for (int d = 1; d < 256; d <<= 1) {
    int t = (tid >= d) ? sd[tid - d] : 0;
    __syncthreads();
    sd[tid] += t;
    __syncthreads();
  }
  if (tid == 255) sums[blockIdx.x] = sd[255];
  int run = sd[tid] - tot;
#pragma unroll
  for (int j = 0; j < 4; ++j) {
    int idx = base + tid * 4 + j;
    if (idx < n) out[idx] = run;
    run += v[j];
  }
}

__global__ __launch_bounds__(64) void k_scan2(int* __restrict__ sums, int n) {
  int tid = threadIdx.x;
  int o = (tid < n) ? sums[tid] : 0;
  int v = o;
  for (int d = 1; d < 64; d <<= 1) {
    int t = __shfl_up(v, d, 64);
    if (tid >= d) v += t;
  }
  if (tid < n) sums[tid] = v - o;  // exclusive
}

// bucket: csr[rp(dst) + epos] = (src, raw w)
__global__ __launch_bounds__(256) void k_bucket2(const int* __restrict__ src,
                                                 const int* __restrict__ dst,
                                                 const float* __restrict__ w,
                                                 const int* __restrict__ row_ptr,
                                                 const int* __restrict__ chunks,
                                                 const int* __restrict__ epos,
                                                 int2* __restrict__ csr, int E) {
  int e = blockIdx.x * 256 + threadIdx.x;
  if (e < E) {
    int d = dst[e];
    int pos = row_ptr[d] + chunks[d >> 10] + epos[e];
    csr[pos] = make_int2(src[e], __float_as_int(w[e]));
  }
}

// dinv[i] = rsqrt(1 + sum of raw w over row i)
__global__ __launch_bounds__(256) void k_deg_dinv(const int* __restrict__ row_ptr,
                                                  const int* __restrict__ chunks,
                                                  const int2* __restrict__ csr,
                                                  float* __restrict__ dinv, int n) {
  int i = blockIdx.x * 256 + threadIdx.x;
  if (i >= n) return;
  const int e0 = row_ptr[i] + chunks[i >> 10];
  const int e1 = row_ptr[i + 1] + chunks[(i + 1) >> 10];
  float s = 1.0f;
  int e = e0;
  for (; e + 4 <= e1; e += 4) {
    float w0 = __int_as_float(csr[e].y), w1 = __int_as_float(csr[e + 1].y);
    float w2 = __int_as_float(csr[e + 2].y), w3 = __int_as_float(csr[e + 3].y);
    s += (w0 + w1) + (w2 + w3);
  }
  for (; e < e1; ++e) s += __int_as_float(csr[e].y);
  dinv[i] = rsqrtf(s);
}

// H = A @ W (bf16 in/out, unscaled) — layer 2
template <int K, int C>
__global__ __launch_bounds__(256, 4) void k_gemm_bf(
    const unsigned short* __restrict__ A, const unsigned short* __restrict__ Wtp,
    unsigned short* __restrict__ H, int n) {
  constexpr int NT = C / 16, KCH = K / 32;
  const int w = threadIdx.x >> 6;
  const int l = threadIdx.x & 63;
  const int lm = l & 15;
  const int lk = (l >> 4) * 8;
  const int row0 = (blockIdx.x * 4 + w) * 16;
  if (row0 >= n) return;
  const int m = row0 + lm;
  const bool valid = m < n;
  const size_t arow = (size_t)(valid ? m : 0) * K;
  short8 af[KCH];
#pragma unroll
  for (int c = 0; c < KCH; ++c)
    af[c] = valid ? *(const short8*)(A + arow + c * 32 + lk)
                  : short8{0, 0, 0, 0, 0, 0, 0, 0};
  f32x4 acc[NT] = {};
  const short8* B = (const short8*)Wtp;
#pragma unroll
  for (int c = 0; c < KCH; ++c)
#pragma unroll
    for (int nt = 0; nt < NT; ++nt)
      acc[nt] = __builtin_amdgcn_mfma_f32_16x16x32_bf16(af[c], B[(c * NT + nt) * 64 + l],
                                                        acc[nt], 0, 0, 0);
  const int orow = row0 + (l >> 4) * 4;
#pragma unroll
  for (int nt = 0; nt < NT; ++nt)
#pragma unroll
    for (int r = 0; r < 4; ++r) {
      int g = orow + r;
      if (g < n) H[(size_t)g * C + nt * 16 + lm] = bf16rne(acc[nt][r]);
    }
}

// out[i] = relu( dinv_i*( dinv_i*h[i] + sum_e dinv[src_e]*w_e*h[src_e] ) + b )
// h bf16; dinv[src] gathered per edge (200KB table, L2-resident).
template <int C, bool OUTF32>
__global__ __launch_bounds__(256) void k_aggregate(
    const int* __restrict__ row_ptr, const int* __restrict__ chunks,
    const int2* __restrict__ csr, const unsigned short* __restrict__ h,
    const float* __restrict__ dinv, const float* __restrict__ bias,
    void* __restrict__ outp, int n) {
  constexpr int LPN = C / 8;      // lanes per node, 16B granules
  constexpr int NPB = 256 / LPN;  // nodes per block
  const int g = threadIdx.x % LPN;
  const int i = blockIdx.x * NPB + threadIdx.x / LPN;
  if (i >= n) return;
  const float di = dinv[i];
  const uint4* h4 = (const uint4*)h;
  uint4 hv = h4[(size_t)i * LPN + g];
  float a0 = di * bflo(hv.x), a1 = di * bfhi(hv.x);
  float a2 = di * bflo(hv.y), a3 = di * bfhi(hv.y);
  float a4 = di * bflo(hv.z), a5 = di * bfhi(hv.z);
  float a6 = di * bflo(hv.w), a7 = di * bfhi(hv.w);
  const int e1 = row_ptr[i + 1] + chunks[(i + 1) >> 10];
  int e = row_ptr[i] + chunks[i >> 10];
  for (; e + 8 <= e1; e += 8) {
    int2 c[8];
    uint4 v[8];
    float ds[8];
#pragma unroll
    for (int j = 0; j < 8; ++j) c[j] = csr[e + j];
#pragma unroll
    for (int j = 0; j < 8; ++j) v[j] = h4[(size_t)c[j].x * LPN + g];
#pragma unroll
    for (int j = 0; j < 8; ++j) ds[j] = dinv[c[j].x];
#pragma unroll
    for (int j = 0; j < 8; ++j) {
      float wj = __int_as_float(c[j].y) * ds[j];
      a0 = fmaf(bflo(v[j].x), wj, a0); a1 = fmaf(bfhi(v[j].x), wj, a1);
      a2 = fmaf(bflo(v[j].y), wj, a2); a3 = fmaf(bfhi(v[j].y), wj, a3);
      a4 = fmaf(bflo(v[j].z), wj, a4); a5 = fmaf(bfhi(v[j].z), wj, a5);
      a6 = fmaf(bflo(v[j].w), wj, a6); a7 = fmaf(bfhi(v[j].w), wj, a7);
    }
  }
  for (; e + 4 <= e1; e += 4) {
    int2 c[4];
    uint4 v[4];
    float ds[4];
#pragma unroll
    for (int j = 0; j < 4; ++j) c[j] = csr[e + j];
#pragma unroll
    for (int j = 0; j < 4; ++j) v[j] = h4[(size_t)c[j].x * LPN + g];
#pragma unroll
    for (int j = 0; j < 4; ++j) ds[j] = dinv[c[j].x];
#pragma unroll
    for (int j = 0; j < 4; ++j) {
      float wj = __int_as_float(c[j].y) * ds[j];
      a0 = fmaf(bflo(v[j].x), wj, a0); a1 = fmaf(bfhi(v[j].x), wj, a1);
      a2 = fmaf(bflo(v[j].y), wj, a2); a3 = fmaf(bfhi(v[j].y), wj, a3);
      a4 = fmaf(bflo(v[j].z), wj, a4); a5 = fmaf(bfhi(v[j].z), wj, a5);
      a6 = fmaf(bflo(v[j].w), wj, a6); a7 = fmaf(bfhi(v[j].w), wj, a7);
    }
  }
  for (; e < e1; ++e) {
    int2 c = csr[e];
    float wj = __int_as_float(c.y) * dinv[c.x];
    uint4 v = h4[(size_t)c.x * LPN + g];
    a0 = fmaf(bflo(v.x), wj, a0); a1 = fmaf(bfhi(v.x), wj, a1);
    a2 = fmaf(bflo(v.y), wj, a2); a3 = fmaf(bfhi(v.y), wj, a3);
    a4 = fmaf(bflo(v.z), wj, a4); a5 = fmaf(bfhi(v.z), wj, a5);
    a6 = fmaf(bflo(v.w), wj, a6); a7 = fmaf(bfhi(v.w), wj, a7);
  }
  const float4* b4 = (const float4*)bias;
  float4 bb0 = b4[g * 2], bb1 = b4[g * 2 + 1];
  a0 = fmaxf(fmaf(a0, di, bb0.x), 0.f); a1 = fmaxf(fmaf(a1, di, bb0.y), 0.f);
  a2 = fmaxf(fmaf(a2, di, bb0.z), 0.f); a3 = fmaxf(fmaf(a3, di, bb0.w), 0.f);
  a4 = fmaxf(fmaf(a4, di, bb1.x), 0.f); a5 = fmaxf(fmaf(a5, di, bb1.y), 0.f);
  a6 = fmaxf(fmaf(a6, di, bb1.z), 0.f); a7 = fmaxf(fmaf(a7, di, bb1.w), 0.f);
  if (OUTF32) {
    float4* o4 = (float4*)outp;
    o4[(size_t)i * (C / 4) + g * 2]     = make_float4(a0, a1, a2, a3);
    o4[(size_t)i * (C / 4) + g * 2 + 1] = make_float4(a4, a5, a6, a7);
  } else {
    uint4 o;
    o.x = (unsigned)bf16rne(a0) | ((unsigned)bf16rne(a1) << 16);
    o.y = (unsigned)bf16rne(a2) | ((unsigned)bf16rne(a3) << 16);
    o.z = (unsigned)bf16rne(a4) | ((unsigned)bf16rne(a5) << 16);
    o.w = (unsigned)bf16rne(a6) | ((unsigned)bf16rne(a7) << 16);
    ((uint4*)outp)[(size_t)i * LPN + g] = o;
  }
}

extern "C" void kernel_launch(void* const* d_in, const int* in_sizes, int n_in,
                              void* d_out, int out_size, void* d_ws, size_t ws_size,
                              hipStream_t stream) {
  (void)n_in; (void)out_size; (void)ws_size;
  const float* x  = (const float*)d_in[0];
  const int*   ei = (const int*)d_in[1];
  const float* ew = (const float*)d_in[2];
  const float* W1 = (const float*)d_in[3];
  const float* b1 = (const float*)d_in[4];
  const float* W2 = (const float*)d_in[5];
  const float* b2 = (const float*)d_in[6];
  float* out = (float*)d_out;

  const int N = in_sizes[0] / 256;  // 50000
  const int E = in_sizes[2];        // 800000
  const int* src = ei;
  const int* dst = ei + E;

  // workspace layout (4-byte units)
  float* ws      = (float*)d_ws;
  float* dinv    = ws;                                   // N          (50176)
  int*   row_ptr = (int*)(ws + 50176);                   // N+1        (50176)
  int*   chunks  = row_ptr + 50176;                      // 64         (256)
  int*   cnt     = chunks + 256;                         // (N+1)*16   (800256)
  int*   epos    = cnt + 800256;                         // E          (800256)
  int2*  csr     = (int2*)(epos + 800256);               // E int2     (1600512)
  unsigned short* h1   = (unsigned short*)((int*)csr + 2 * 800256);  // N*128 bf16
  unsigned short* o1   = h1 + (size_t)50000 * 128;       // N*128 bf16
  unsigned short* wtp1 = o1 + (size_t)50000 * 128;       // 128*256 bf16
  unsigned short* wtp2 = wtp1 + 128 * 256;               // 64*128 bf16
  unsigned short* h2   = h1;                             // alias (h1 dead after agg1)

  const int nz = (N + 1) * CPAD;
  const int nchunks = (N + 1 + SCAN_CHUNK - 1) / SCAN_CHUNK;  // 49
  const int CB = (E + 1023) / 1024;                           // 782 count blocks
  const int GB = (N + 63) / 64;                               // 782 gemm1 blocks
  // parity interleave requires CB == GB (both 782 for this shape)

  k_prep<<<(nz + 255) / 256, 256, 0, stream>>>(cnt, nz, W1, wtp1, W2, wtp2);
  k_count_gemm1<<<CB + GB, 256, 0, stream>>>(dst, cnt, epos, E, CB, x, wtp1, h1, N);
  k_scan1<<<nchunks, 256, 0, stream>>>(cnt, row_ptr, chunks, N + 1);
  k_scan2<<<1, 64, 0, stream>>>(chunks, nchunks);
  k_bucket2<<<(E + 255) / 256, 256, 0, stream>>>(src, dst, ew, row_ptr, chunks,
                                                 epos, csr, E);
  k_deg_dinv<<<(N + 255) / 256, 256, 0, stream>>>(row_ptr, chunks, csr, dinv, N);

  k_aggregate<128, false><<<(N + 15) / 16, 256, 0, stream>>>(row_ptr, chunks, csr,
                                                             h1, dinv, b1, o1, N);
  k_gemm_bf<128, 64><<<(N + 63) / 64, 256, 0, stream>>>(o1, wtp2, h2, N);
  k_aggregate<64, true><<<(N + 31) / 32, 256, 0, stream>>>(row_ptr, chunks, csr,
                                                           h2, dinv, b2, out, N);
}